// Round 7
// baseline (143.225 us; speedup 1.0000x reference)
//
#include <hip/hip_runtime.h>
#include <math.h>

// GCN graph-matching net. Verified reductions (R0-R5, absmax ~0):
//  - K off-diag values only used via (K != 0) -> class-match pattern; edge MLPs dead.
//  - normA @ u collapses to O(N) inclusion-exclusion; x stays rank<=7.
//  - Multiplicative sinkhorn: A = 2^(t - rowmax) once; steps u=1/(Av), v=1/(A^T u).
// R6: 4-wave quad-parallel sinkhorn, 60 barriers -> 39.2us (best so far).
// R7-R11: wave-0-only variants all 49-59us (remat of LDS loads, VGPR cap, icache).
// R12: flag-sync replaced barriers -> 46.9us. s_barrier is CHEAP; the half-step cost
//   is the cross-wave LDS round trip itself. Protocol tweaks dead end.
// R13: REDUNDANT-WAVE SINKHORN. All 4 waves build the FULL A+A^T in registers
//   (128 VGPR/lane) from LDS-staged t via e2f(ld(t)-rm) -- a compute chain the
//   allocator cannot rematerialize (R9 lesson: bare loads get demoted; chains
//   don't). Each wave runs all 19 remaining half-steps fully in-wave (bpermute
//   exchange, R10-verified bit-exact) -> ZERO cross-wave sync in the loop. Recon
//   and output are in-wave too: slot s==wv is the thread's own (r,q) fragment;
//   u[r]=rcpf(sel4(us,wv)), v[r]=rcpf(sel4(vs,wv)). Caller state zeroed across
//   sinkhorns via R9's spill infra (R7 lesson). Loop kept #pragma unroll 1 (R11
//   icache lesson). Per sinkhorn: 1 staging + 2 barriers; half-step ~300cy.

#define SK_SCALE 28.853900817779268f   // (1/TAU = 20) * log2(e)

template<int CTRL>
__device__ __forceinline__ float dppf(float x) {
    int xi = __float_as_int(x);
    int rr = __builtin_amdgcn_update_dpp(xi, xi, CTRL, 0xF, 0xF, false);
    return __int_as_float(rr);
}
__device__ __forceinline__ float quad_sum(float v) {   // sum over lane&3 quad
    v += dppf<0xB1>(v); v += dppf<0x4E>(v); return v;
}
__device__ __forceinline__ float quad_max(float v) {
    v = fmaxf(v, dppf<0xB1>(v)); v = fmaxf(v, dppf<0x4E>(v)); return v;
}
__device__ __forceinline__ float e2f(float x) { return __builtin_amdgcn_exp2f(x); }
__device__ __forceinline__ float rcpf(float x) { return __builtin_amdgcn_rcpf(x); }
__device__ __forceinline__ float dot4(const float4 a, const float4 b) {
    return a.x*b.x + a.y*b.y + a.z*b.z + a.w*b.w;
}
__device__ __forceinline__ void fma4(float4& a, float b, const float4 c) {
    a.x += b*c.x; a.y += b*c.y; a.z += b*c.z; a.w += b*c.w;
}
__device__ __forceinline__ void add4(float4& a, const float4 c) {
    a.x += c.x; a.y += c.y; a.z += c.z; a.w += c.w;
}
__device__ __forceinline__ void ld16(const float* p, float* o) {
    #pragma unroll
    for (int t = 0; t < 4; ++t) {
        float4 v = *(const float4*)(p + 4*t);
        o[4*t+0]=v.x; o[4*t+1]=v.y; o[4*t+2]=v.z; o[4*t+3]=v.w;
    }
}
// transpose read of a 64x64 stride-64 natural array: o[m] = X[16q+m][r]
__device__ __forceinline__ void ldT(const float* X, int r, int q, float* o) {
    #pragma unroll
    for (int m = 0; m < 16; ++m) o[m] = X[(16*q + m)*64 + r];
}
__device__ __forceinline__ float dotsum16(const float* a, const float* b) {
    float s0=0,s1=0,s2=0,s3=0;
    #pragma unroll
    for (int t = 0; t < 4; ++t) {
        s0 += a[4*t+0]*b[4*t+0]; s1 += a[4*t+1]*b[4*t+1];
        s2 += a[4*t+2]*b[4*t+2]; s3 += a[4*t+3]*b[4*t+3];
    }
    return (s0+s1)+(s2+s3);
}
__device__ __forceinline__ float sum16(const float* a) {
    float s0=0,s1=0,s2=0,s3=0;
    #pragma unroll
    for (int t = 0; t < 4; ++t) {
        s0 += a[4*t+0]; s1 += a[4*t+1]; s2 += a[4*t+2]; s3 += a[4*t+3];
    }
    return (s0+s1)+(s2+s3);
}
__device__ __forceinline__ void stage16(float* dst, const float* v, float sc) {
    #pragma unroll
    for (int t = 0; t < 4; ++t)
        *(float4*)(dst + 4*t) = make_float4(v[4*t+0]*sc, v[4*t+1]*sc,
                                            v[4*t+2]*sc, v[4*t+3]*sc);
}
// Static-index selects (rule #20: no runtime register-array indexing).
__device__ __forceinline__ float sel4(const float* v, int k) {
    float w = v[0];
    w = (k == 1) ? v[1] : w;
    w = (k == 2) ? v[2] : w;
    w = (k == 3) ? v[3] : w;
    return w;
}
__device__ __forceinline__ float selw4(float a0, float a1, float a2, float a3, int k) {
    float w = a0;
    w = (k == 1) ? a1 : w;
    w = (k == 2) ? a2 : w;
    w = (k == 3) ? a3 : w;
    return w;
}
// o[m] = value of w in lane 4m+q; byte addr = 4*(4m+q) = q4 + 16m. In-wave crossbar.
__device__ __forceinline__ void bperm16(int q4, float w, float* o) {
    #pragma unroll
    for (int m = 0; m < 16; ++m)
        o[m] = __int_as_float(__builtin_amdgcn_ds_bpermute(q4 + 16*m, __float_as_int(w)));
}

// Redundant-wave multiplicative sinkhorn, 20 steps.
// 256-wide preamble: thread (r,q) stages its t row-fragment (TN[r][16q+m]=tq[m]) and
// t^T fragment (TT[r][16q+m]=tt[m]=t[16q+m][r]), computes rm[r] (quad_max) and it0's
// u0[r]=1/rowsum (staged). Then EVERY wave builds the full A (aq[s][j]=e2f(TN[16s+
// rr][16q+j]-rm[16s+rr])) and A^T (att[s][j]=e2f(TT[16s+rr][16q+j]-rm[16q+j])) in
// 128 VGPRs and runs its 1..19 with in-wave bpermute exchange -- reduction tree
// (in-thread sum16 + quad-DPP) identical to R6, so bit-identical results. Recon/out
// fully in-wave: slot s==wv is the thread's own (r,q) fragment.
// Caller must carry ZERO live register state across this call (R7 lesson).
__device__ __forceinline__ void sk_red(const float* tq, const float* tt,
                                       int r, int q, int wv, int lane,
                                       float* TN, float* TT, float* up, float* rmp,
                                       float* sv, float* st, float* outp) {
    __syncthreads();   // defensive: all waves' previous-phase LDS reads retired
    // ---- 256-wide preamble ----
    float rm = tq[0];
    #pragma unroll
    for (int m = 1; m < 16; ++m) rm = fmaxf(rm, tq[m]);
    rm = quad_max(rm);
    stage16(TN + r*68 + 16*q, tq, 1.0f);
    stage16(TT + r*68 + 16*q, tt, 1.0f);
    {
        float a0[16];
        #pragma unroll
        for (int j = 0; j < 16; ++j) a0[j] = e2f(tq[j] - rm);
        float u0 = rcpf(quad_sum(sum16(a0)));     // it0 (row, v = 1)
        if (q == 0) { rmp[r] = rm; up[r] = u0; }
    }
    __syncthreads();   // staged t / rm / u0 visible to all waves
    // ---- wave-redundant: full A + A^T in registers ----
    const int rr = lane >> 2;      // q == lane & 3
    const int q4 = q << 2;
    float rms[4];
    #pragma unroll
    for (int s = 0; s < 4; ++s) rms[s] = rmp[16*s + rr];
    float rmq[16]; ld16(rmp + 16*q, rmq);
    float aq[4][16], att[4][16];
    #pragma unroll
    for (int s = 0; s < 4; ++s) {
        float t_[16];
        ld16(TN + (16*s + rr)*68 + 16*q, t_);
        #pragma unroll
        for (int j = 0; j < 16; ++j) aq[s][j] = e2f(t_[j] - rms[s]);
    }
    #pragma unroll
    for (int s = 0; s < 4; ++s) {
        float t_[16];
        ld16(TT + (16*s + rr)*68 + 16*q, t_);
        #pragma unroll
        for (int j = 0; j < 16; ++j) att[s][j] = e2f(t_[j] - rmq[j]);
    }
    float uq[16]; ld16(up + 16*q, uq);            // it0 u distributed
    float us[4], vs[4];
    float wvv = 0.0f;
    #pragma unroll 1
    for (int p = 0; p < 9; ++p) {                 // its 1..18: 9 x (col, row)
        #pragma unroll
        for (int s = 0; s < 4; ++s) vs[s] = quad_sum(dotsum16(att[s], uq));
        wvv = rcpf(sel4(vs, q));                  // v for col 16q+rr
        float vq[16]; bperm16(q4, wvv, vq);
        #pragma unroll
        for (int s = 0; s < 4; ++s) us[s] = quad_sum(dotsum16(aq[s], vq));
        float wu = rcpf(sel4(us, q));             // u for row 16q+rr
        bperm16(q4, wu, uq);                      // it-even u distributed
    }
    {   // it19 (col)
        #pragma unroll
        for (int s = 0; s < 4; ++s) vs[s] = quad_sum(dotsum16(att[s], uq));
        wvv = rcpf(sel4(vs, q));
    }
    float vq[16]; bperm16(q4, wvv, vq);           // it19 v distributed
    float u_ = rcpf(sel4(us, wv));                // u[r]  (it18 raw sum, own row)
    float v_ = rcpf(sel4(vs, wv));                // v[r]  (it19 raw sum, own col)
    if (outp) {
        #pragma unroll
        for (int t = 0; t < 4; ++t) {
            float4 o4;
            #pragma unroll
            for (int j = 0; j < 4; ++j) {
                int e = 4*t + j;
                float an = selw4(aq[0][e], aq[1][e], aq[2][e], aq[3][e], wv);
                float ov = an * u_ * vq[e];
                if (j == 0) o4.x = ov; else if (j == 1) o4.y = ov;
                else if (j == 2) o4.z = ov; else o4.w = ov;
            }
            *(float4*)(outp + r*64 + 16*q + 4*t) = o4;
        }
    } else {
        #pragma unroll
        for (int j = 0; j < 16; ++j) {
            float an = selw4(aq[0][j], aq[1][j], aq[2][j], aq[3][j], wv);
            float at = selw4(att[0][j], att[1][j], att[2][j], att[3][j], wv);
            sv[j] = an * u_ * vq[j];              // s[r][16q+j]
            st[j] = at * uq[j] * v_;              // s[16q+j][r]
        }
    }
}

// normA matvec, dual vectors x dual orientations, ONE barrier. u2==nullptr -> ones.
__device__ __forceinline__ void matvec_dual(const float* u1, const float* u1t,
                                            const float* u2, const float* u2t,
                                            const float* mmq, const float* dqv,
                                            const float* mmt, const float* dqt,
                                            float* o1, float* o1t, float* o2, float* o2t,
                                            int q, int r,
                                            float* WR1, float* WC1, float* WR2, float* WC2) {
    float rs1=0, rs2=0, cs1=0, cs2=0;
    #pragma unroll
    for (int m = 0; m < 16; ++m) {
        float md = mmq[m]*dqv[m], mdt = mmt[m]*dqt[m];
        rs1 += md * u1[m];               cs1 += mdt * u1t[m];
        rs2 += md * (u2 ? u2[m] : 1.0f); cs2 += mdt * (u2t ? u2t[m] : 1.0f);
    }
    rs1 = quad_sum(rs1); rs2 = quad_sum(rs2);
    cs1 = quad_sum(cs1); cs2 = quad_sum(cs2);
    if (q == 0) { WR1[r]=rs1; WR2[r]=rs2; WC1[r]=cs1; WC2[r]=cs2; }
    __syncthreads();
    float wr1[16], wc1[16], wr2[16], wc2[16];
    ld16(WR1 + 16*q, wr1); ld16(WC1 + 16*q, wc1);
    ld16(WR2 + 16*q, wr2); ld16(WC2 + 16*q, wc2);
    float W1 = quad_sum(sum16(wc1));
    float W2 = quad_sum(sum16(wc2));
    #pragma unroll
    for (int m = 0; m < 16; ++m) {
        float d = dqv[m], mm = mmq[m];
        float u1m = u1[m], u2m = u2 ? u2[m] : 1.0f;
        float z1 = mm*d*u1m, z2 = mm*d*u2m;
        o1[m] = d*((1.0f+mm)*d*u1m + mm*(W1 - rs1 - wc1[m] + z1));
        o2[m] = d*((1.0f+mm)*d*u2m + mm*(W2 - rs2 - wc2[m] + z2));
        float dt = dqt[m], mt = mmt[m];
        float u1tm = u1t[m], u2tm = u2t ? u2t[m] : 1.0f;
        float z1t = mt*dt*u1tm, z2t = mt*dt*u2tm;
        o1t[m] = dt*((1.0f+mt)*dt*u1tm + mt*(W1 - wr1[m] - cs1 + z1t));
        o2t[m] = dt*((1.0f+mt)*dt*u2tm + mt*(W2 - wr2[m] - cs2 + z2t));
    }
}

extern "C" __global__ __launch_bounds__(256, 1)
void gcn_match_kernel(const float* ego, const float* cav,
                      const float* nw1, const float* nb1, const float* nw2, const float* nb2,
                      const float* sw0, const float* sb0, const float* cw0, const float* cb0,
                      const float* kw0, const float* kb0,
                      const float* sw1, const float* sb1, const float* cw1, const float* cb1,
                      const float* kw1, const float* kb1,
                      const float* fcw, const float* fcb,
                      float* out) {
    __shared__ __align__(16) float sh_hT1[64 * 68];   // ego h^T | dots | staged t (nat)
    __shared__ __align__(16) float sh_hT2[64 * 68];   // cav h^T | dots^T | staged t^T
    // Union scratch: setup uses [w2:2048 | f1:2304 | f2:2304]; after P2 those die and
    // the same space holds the caller-state spill [T1B:4096 | SB:4096 | V0:4096].
    __shared__ __align__(16) float sh_scr[12288];
    float* const SH_W2  = sh_scr;
    float* const SH_F1  = sh_scr + 2048;
    float* const SH_F2  = sh_scr + 4352;
    float* const SH_T1B = sh_scr;          // t1 base, natural (64x64, stride 64)
    float* const SH_SB  = sh_scr + 4096;   // sacc base, natural
    float* const SH_V0  = sh_scr + 8192;   // v0 natural; later sacc natural
    __shared__ __align__(16) float sh_nw1[320];
    __shared__ __align__(16) float sh_nb1[64], sh_nb2[32];
    __shared__ __align__(16) float sh_cls1[64], sh_cf1[64], sh_cls2[64], sh_cf2[64];
    __shared__ __align__(16) float sh_n1[64], sh_n2[64], sh_Dr[64], sh_Dc[64];
    __shared__ __align__(16) float sh_up[64], sh_rmp[64];
    __shared__ __align__(16) float sh_WR1[64], sh_WC1[64], sh_WR2[64], sh_WC2[64];
    __shared__ __align__(16) float sh_sw0[16], sh_sb0[16], sh_cw0[16], sh_cb0[16];
    __shared__ __align__(16) float sh_sb1[16], sh_cb1[16];
    __shared__ __align__(16) float sh_sw1[256], sh_cw1[256];
    __shared__ __align__(16) float sh_kw0[16], sh_kw1[16], sh_fcw[16];
    __shared__ float sh_kb[4];        // kb0, kb1, fcb
    __shared__ float sh_avec[7 * 16];
    __shared__ float sh_coef[18];

    const int tid = threadIdx.x;
    const int wv = tid >> 6, lane = tid & 63;
    const int r = tid >> 2, q = tid & 3;

    // ================= P0a: stage everything (one parallel load round) ==========
    ((float4*)SH_W2)[tid]       = ((const float4*)nw2)[tid];
    ((float4*)SH_W2)[tid + 256] = ((const float4*)nw2)[tid + 256];
    if (tid < 80)       ((float4*)sh_nw1)[tid]      = ((const float4*)nw1)[tid];
    else if (tid < 96)  ((float4*)sh_nb1)[tid-80]   = ((const float4*)nb1)[tid-80];
    else if (tid < 104) ((float4*)sh_nb2)[tid-96]   = ((const float4*)nb2)[tid-96];
    else if (tid < 108) ((float4*)sh_sw0)[tid-104]  = ((const float4*)sw0)[tid-104];
    else if (tid < 112) ((float4*)sh_sb0)[tid-108]  = ((const float4*)sb0)[tid-108];
    else if (tid < 116) ((float4*)sh_cw0)[tid-112]  = ((const float4*)cw0)[tid-112];
    else if (tid < 120) ((float4*)sh_cb0)[tid-116]  = ((const float4*)cb0)[tid-116];
    else if (tid < 124) ((float4*)sh_sb1)[tid-120]  = ((const float4*)sb1)[tid-120];
    else if (tid < 128) ((float4*)sh_cb1)[tid-124]  = ((const float4*)cb1)[tid-124];
    else if (tid < 192) ((float4*)sh_sw1)[tid-128]  = ((const float4*)sw1)[tid-128];
    else                ((float4*)sh_cw1)[tid-192]  = ((const float4*)cw1)[tid-192];
    if (tid < 4)        ((float4*)sh_kw0)[tid]      = ((const float4*)kw0)[tid];
    else if (tid < 8)   ((float4*)sh_kw1)[tid-4]    = ((const float4*)kw1)[tid-4];
    else if (tid < 12)  ((float4*)sh_fcw)[tid-8]    = ((const float4*)fcw)[tid-8];
    else if (tid == 12) sh_kb[0] = kb0[0];
    else if (tid == 13) sh_kb[1] = kb1[0];
    else if (tid == 14) sh_kb[2] = fcb[0];
    if (tid < 64) { sh_cls1[tid] = ego[tid*8+6]; sh_cf1[tid] = ego[tid*8+7]; }
    else if (tid < 128) { int j = tid-64; sh_cls2[j] = cav[j*8+6]; sh_cf2[j] = cav[j*8+7]; }
    __syncthreads();

    // ================= P0b: hidden MLP (transposed store), 4 waves ==============
    {
        float4 ea = ((const float4*)ego)[lane*2], eb = ((const float4*)ego)[lane*2+1];
        float4 ca = ((const float4*)cav)[lane*2], cb = ((const float4*)cav)[lane*2+1];
        #pragma unroll
        for (int kk = 0; kk < 16; ++kk) {
            int k = 16*wv + kk;
            float b1 = sh_nb1[k];
            float w0 = sh_nw1[k],       w1 = sh_nw1[64+k],  w2_ = sh_nw1[128+k];
            float w3 = sh_nw1[192+k],   w4 = sh_nw1[256+k];
            sh_hT1[k*68 + lane] = fmaxf(b1 + ea.y*w0 + ea.z*w1 + ea.w*w2_ + eb.x*w3 + eb.y*w4, 0.0f);
            sh_hT2[k*68 + lane] = fmaxf(b1 + ca.y*w0 + ca.z*w1 + ca.w*w2_ + cb.x*w3 + cb.y*w4, 0.0f);
        }
    }
    __syncthreads();

    // ================= P1: GEMMs (waves 0,1) + avec/coef (wave 2) ===============
    if (wv < 2) {
        const float* HT = (wv == 0) ? sh_hT1 : sh_hT2;
        float* F  = (wv == 0) ? SH_F1 : SH_F2;
        float* NN = (wv == 0) ? sh_n1 : sh_n2;
        const int rr = lane >> 2, oq = lane & 3;
        float4 accA[4], accB[4];
        #pragma unroll
        for (int m = 0; m < 4; ++m) { accA[m] = make_float4(0,0,0,0); accB[m] = accA[m]; }
        #pragma unroll 4
        for (int k = 0; k < 64; ++k) {
            float4 hq = *(const float4*)(HT + k*68 + 4*rr);
            float4 wA = *(const float4*)(SH_W2 + k*32 + 4*oq);
            float4 wB = *(const float4*)(SH_W2 + k*32 + 16 + 4*oq);
            fma4(accA[0], hq.x, wA); fma4(accB[0], hq.x, wB);
            fma4(accA[1], hq.y, wA); fma4(accB[1], hq.y, wB);
            fma4(accA[2], hq.z, wA); fma4(accB[2], hq.z, wB);
            fma4(accA[3], hq.w, wA); fma4(accB[3], hq.w, wB);
        }
        float4 b2a = *(const float4*)(sh_nb2 + 4*oq);
        float4 b2b = *(const float4*)(sh_nb2 + 16 + 4*oq);
        float sq[4];
        #pragma unroll
        for (int m = 0; m < 4; ++m) {
            add4(accA[m], b2a); add4(accB[m], b2b);
            int row = 4*rr + m;
            *(float4*)(F + row*36 + 4*oq)      = accA[m];
            *(float4*)(F + row*36 + 16 + 4*oq) = accB[m];
            float q2 = dot4(accA[m], accA[m]) + dot4(accB[m], accB[m]);
            q2 += dppf<0xB1>(q2); q2 += dppf<0x4E>(q2);
            sq[m] = q2;
        }
        if (oq == 0) {
            #pragma unroll
            for (int m = 0; m < 4; ++m)
                NN[4*rr + m] = fmaxf(sqrtf(sq[m]), 1e-8f);
        }
    } else if (wv == 2) {
        if (lane < 16) {   // avec from LDS-staged weights
            int o = lane;
            float ax=0, av=0, as_=0, aw=0, au=0, ae=0, a1=0;
            #pragma unroll
            for (int k = 0; k < 16; ++k) {
                float s0k = sh_sw0[k], c0k = sh_cw0[k], b0k = sh_sb0[k] + sh_cb0[k];
                float s1ko = sh_sw1[k*16+o], c1ko = sh_cw1[k*16+o];
                ax += s0k*s1ko;  av += c0k*s1ko + s0k*c1ko;  as_ += s1ko;
                aw += c0k*c1ko;  au += c1ko;  ae += b0k*c1ko;  a1 += b0k*s1ko;
            }
            a1 += sh_sb1[o] + sh_cb1[o];
            sh_avec[0*16+o]=ax; sh_avec[1*16+o]=av; sh_avec[2*16+o]=as_;
            sh_avec[3*16+o]=aw; sh_avec[4*16+o]=au; sh_avec[5*16+o]=ae;
            sh_avec[6*16+o]=a1;
        }
        if (lane < 18) {   // coef (same wave: avec writes visible via lgkmcnt)
            int t = lane; float c = 0.0f;
            if (t == 0)      { for (int k = 0; k < 16; ++k) c += sh_sw0[k]*sh_kw0[k]; }
            else if (t == 1) { for (int k = 0; k < 16; ++k) c += sh_cw0[k]*sh_kw0[k]; }
            else if (t == 2) { for (int k = 0; k < 16; ++k) c += (sh_sb0[k]+sh_cb0[k])*sh_kw0[k]; c += sh_kb[0]; }
            else if (t < 10) { int v = t-3;
                for (int o = 0; o < 16; ++o) c += sh_avec[v*16+o]*sh_kw1[o];
                if (v == 6) c += sh_kb[1];
            } else if (t < 17) { int v = t-10;
                for (int o = 0; o < 16; ++o) c += sh_avec[v*16+o]*sh_fcw[o];
                if (v == 6) c += sh_kb[2];
            } else { for (int o = 0; o < 16; ++o) c += sh_fcw[o]; }
            sh_coef[t] = c;
        }
    }
    __syncthreads();

    // ================= P2: dots (all 4 waves, natural + transposed) + mm/degrees =
    {
        const int sc = lane & 15, rc = lane >> 4;
        float dt[4][4];
        #pragma unroll
        for (int m = 0; m < 4; ++m)
            #pragma unroll
            for (int k = 0; k < 4; ++k) dt[m][k] = 0.0f;
        for (int kq = 0; kq < 8; ++kq) {
            float4 f2q[4];
            #pragma unroll
            for (int k = 0; k < 4; ++k)
                f2q[k] = *(const float4*)(SH_F2 + (sc + 16*k)*36 + 4*kq);
            #pragma unroll
            for (int m = 0; m < 4; ++m) {
                int rrow = 16*m + 4*wv + rc;
                float4 f1q = *(const float4*)(SH_F1 + rrow*36 + 4*kq);
                #pragma unroll
                for (int k = 0; k < 4; ++k) dt[m][k] += dot4(f1q, f2q[k]);
            }
        }
        #pragma unroll
        for (int m = 0; m < 4; ++m) {
            int rrow = 16*m + 4*wv + rc;
            #pragma unroll
            for (int k = 0; k < 4; ++k) {
                sh_hT1[rrow*68 + sc + 16*k] = dt[m][k];       // dots natural
                sh_hT2[(sc + 16*k)*68 + rrow] = dt[m][k];     // dots transposed
            }
        }
    }
    float mmq[16], mmt[16], cfq[16], cft[16];
    float Drr, Dcr;
    {
        float c2q[16], c1q[16], f2v[16], f1v[16];
        ld16(sh_cls2 + 16*q, c2q); ld16(sh_cls1 + 16*q, c1q);
        ld16(sh_cf2 + 16*q, f2v);  ld16(sh_cf1 + 16*q, f1v);
        const float cls1r = sh_cls1[r], cls2r = sh_cls2[r];
        const float cf1r = sh_cf1[r],  cf2r  = sh_cf2[r];
        float dr = 0, dc = 0;
        #pragma unroll
        for (int m = 0; m < 16; ++m) {
            mmq[m] = (cls1r == c2q[m]) ? 1.0f : 0.0f;
            mmt[m] = (c1q[m] == cls2r) ? 1.0f : 0.0f;
            dr += mmq[m]; dc += mmt[m];
            cfq[m] = sqrtf(cf1r * f2v[m]);
            cft[m] = sqrtf(f1v[m] * cf2r);
        }
        Drr = quad_sum(dr);
        Dcr = quad_sum(dc);
        if (q == 0) { sh_Dr[r] = Drr; sh_Dc[r] = Dcr; }
    }
    __syncthreads();

    // ================= P3: dinv + x0, both orientations ==========================
    float dqv[16], dqt[16], x0[16], x0t[16];
    {
        float dcq[16], drq[16], n2q[16], n1q[16], dotq[16], dotTq[16];
        ld16(sh_Dc + 16*q, dcq); ld16(sh_Dr + 16*q, drq);
        ld16(sh_n2 + 16*q, n2q); ld16(sh_n1 + 16*q, n1q);
        ld16(sh_hT1 + r*68 + 16*q, dotq);
        ld16(sh_hT2 + r*68 + 16*q, dotTq);
        float Tdeg = quad_sum(sum16(dcq));
        const float n1r = sh_n1[r], n2r = sh_n2[r];
        #pragma unroll
        for (int m = 0; m < 16; ++m) {
            dqv[m] = (mmq[m] != 0.0f) ? (1.0f / sqrtf(Tdeg - Drr - dcq[m] + 3.0f)) : 1.0f;
            dqt[m] = (mmt[m] != 0.0f) ? (1.0f / sqrtf(Tdeg - drq[m] - Dcr + 3.0f)) : 1.0f;
            x0[m]  = mmq[m] * cfq[m] * (dotq[m]  / (n1r * n2q[m]));
            x0t[m] = mmt[m] * cft[m] * (dotTq[m] / (n1q[m] * n2r));
        }
    }

    // ================= matvec A: v0 = normA x0, oe = normA 1 =====================
    float v0[16], v0t[16], oe[16], oet[16];
    matvec_dual(x0, x0t, nullptr, nullptr, mmq, dqv, mmt, dqt,
                v0, v0t, oe, oet, q, r, sh_WR1, sh_WC1, sh_WR2, sh_WC2);

    // ================= t0 (both) + NATURAL t1/sacc bases; spill state ============
    // Transposed bases re-read from the natural spill after sk0 (nat/transposed
    // duality is bit-exact; verified across R9-R11).
    float t0q[16], t0t[16];
    {
        float c0 = sh_coef[0], c1 = sh_coef[1], c2 = sh_coef[2];
        float ctx = sh_coef[3], ctv = sh_coef[4];
        float ce_ = sh_coef[8], ct1 = sh_coef[9];
        float csx = sh_coef[10], csv = sh_coef[11];
        float ce2 = sh_coef[15], cs1 = sh_coef[16];
        float t1b[16], sbse[16];
        #pragma unroll
        for (int m = 0; m < 16; ++m) {
            t0q[m] = (c0*x0[m]  + c1*v0[m]  + c2) * SK_SCALE;
            t0t[m] = (c0*x0t[m] + c1*v0t[m] + c2) * SK_SCALE;
            t1b[m]  = ctx*x0[m]  + ctv*v0[m]  + ct1 + ce_*oe[m];
            sbse[m] = csx*x0[m]  + csv*v0[m]  + cs1 + ce2*oe[m];
        }
        stage16(SH_T1B + r*64 + 16*q, t1b, 1.0f);   // spill (f1/f2/w2 dead post-P2)
        stage16(SH_SB  + r*64 + 16*q, sbse, 1.0f);
        stage16(SH_V0  + r*64 + 16*q, v0, 1.0f);
    }
    // From here, NO per-thread register state survives across sinkhorn calls.

    // ================= sinkhorn0 (redundant-wave) -> s0 ==========================
    float s0v[16], s0t[16];
    sk_red(t0q, t0t, r, q, wv, lane, sh_hT1, sh_hT2, sh_up, sh_rmp, s0v, s0t, nullptr);

    // ---- recompute mm/dq (bit-identical: same formulas, same LDS inputs) --------
    {
        float c2q[16], c1q[16];
        ld16(sh_cls2 + 16*q, c2q); ld16(sh_cls1 + 16*q, c1q);
        const float cls1r = sh_cls1[r], cls2r = sh_cls2[r];
        #pragma unroll
        for (int m = 0; m < 16; ++m) {
            mmq[m] = (cls1r == c2q[m]) ? 1.0f : 0.0f;
            mmt[m] = (c1q[m] == cls2r) ? 1.0f : 0.0f;
        }
        float dcq[16], drq[16];
        ld16(sh_Dc + 16*q, dcq); ld16(sh_Dr + 16*q, drq);
        float Tdeg = quad_sum(sum16(dcq));
        const float Dr2 = sh_Dr[r], Dc2 = sh_Dc[r];   // == P3's quad_sum values
        #pragma unroll
        for (int m = 0; m < 16; ++m) {
            dqv[m] = (mmq[m] != 0.0f) ? (1.0f / sqrtf(Tdeg - Dr2 - dcq[m] + 3.0f)) : 1.0f;
            dqt[m] = (mmt[m] != 0.0f) ? (1.0f / sqrtf(Tdeg - drq[m] - Dc2 + 3.0f)) : 1.0f;
        }
    }
    // ---- reload v0 (natural + transpose-read; sk_red's barriers give visibility) -
    {
        float v0n[16], v0tn[16];
        ld16(SH_V0 + r*64 + 16*q, v0n);
        ldT(SH_V0, r, q, v0tn);
        #pragma unroll
        for (int m = 0; m < 16; ++m) { v0[m] = v0n[m]; v0t[m] = v0tn[m]; }
    }

    // ================= matvec B (v0, s0) -> t1, sacc =============================
    // (internal barrier orders V0 reads above before the sacc spill below)
    float ov[16], ovt[16], os[16], ost[16];
    matvec_dual(v0, v0t, s0v, s0t, mmq, dqv, mmt, dqt,
                ov, ovt, os, ost, q, r, sh_WR1, sh_WC1, sh_WR2, sh_WC2);
    float t1q[16], t1t[16];
    {
        float cts = sh_coef[5], cw_ = sh_coef[6], cu_ = sh_coef[7];
        float css = sh_coef[12], cw2 = sh_coef[13], cu2 = sh_coef[14];
        float t1b_[16], t1bt_[16], sbse_[16], sacc[16];
        ld16(SH_T1B + r*64 + 16*q, t1b_);
        ldT(SH_T1B, r, q, t1bt_);
        ld16(SH_SB + r*64 + 16*q, sbse_);
        #pragma unroll
        for (int m = 0; m < 16; ++m) {
            t1q[m] = (t1b_[m]  + cts*s0v[m] + cw_*ov[m]  + cu_*os[m])  * SK_SCALE;
            t1t[m] = (t1bt_[m] + cts*s0t[m] + cw_*ovt[m] + cu_*ost[m]) * SK_SCALE;
            sacc[m] = sbse_[m] + css*s0v[m] + cw2*ov[m]  + cu2*os[m];
        }
        // spill sacc (natural) into V0's slot: v0 consumed; V0 reads were all before
        // matvec B's internal barrier -> no race.
        stage16(SH_V0 + r*64 + 16*q, sacc, 1.0f);
    }

    // ================= sinkhorn1 (redundant-wave) -> s1 ==========================
    float s1v[16], s1t[16];
    sk_red(t1q, t1t, r, q, wv, lane, sh_hT1, sh_hT2, sh_up, sh_rmp, s1v, s1t, nullptr);

    // ================= t2 = (sacc + c17*s1)^T, then sinkhorn2 -> output ==========
    float t2q[16], t2t[16];
    {
        float c17 = sh_coef[17];
        float saccN[16], saccT[16];
        ld16(SH_V0 + r*64 + 16*q, saccN);     // visibility via sk1's barriers
        ldT(SH_V0, r, q, saccT);
        #pragma unroll
        for (int m = 0; m < 16; ++m) {
            // sacct (+= c17*s1t) feeds sk2's NATURAL input; sacc feeds transposed.
            t2q[m] = (saccT[m] + c17 * s1t[m]) * SK_SCALE;
            t2t[m] = (saccN[m] + c17 * s1v[m]) * SK_SCALE;
        }
    }
    sk_red(t2q, t2t, r, q, wv, lane, sh_hT1, sh_hT2, sh_up, sh_rmp,
           nullptr, nullptr, out);
    // all 256 threads store their own 16-output slice inside sk_red.
}

extern "C" void kernel_launch(void* const* d_in, const int* in_sizes, int n_in,
                              void* d_out, int out_size, void* d_ws, size_t ws_size,
                              hipStream_t stream) {
    const float* ego = (const float*)d_in[0];
    const float* cav = (const float*)d_in[1];
    const float* nw1 = (const float*)d_in[2];
    const float* nb1 = (const float*)d_in[3];
    const float* nw2 = (const float*)d_in[4];
    const float* nb2 = (const float*)d_in[5];
    // d_in[6..9] = edge MLP weights: dead code (edge values only feed the (K!=0) pattern)
    const float* sw0 = (const float*)d_in[10];
    const float* sb0 = (const float*)d_in[11];
    const float* cw0 = (const float*)d_in[12];
    const float* cb0 = (const float*)d_in[13];
    const float* kw0 = (const float*)d_in[14];
    const float* kb0 = (const float*)d_in[15];
    const float* sw1 = (const float*)d_in[16];
    const float* sb1 = (const float*)d_in[17];
    const float* cw1 = (const float*)d_in[18];
    const float* cb1 = (const float*)d_in[19];
    const float* kw1 = (const float*)d_in[20];
    const float* kb1 = (const float*)d_in[21];
    const float* fcw = (const float*)d_in[22];
    const float* fcb = (const float*)d_in[23];

    gcn_match_kernel<<<dim3(1), dim3(256), 0, stream>>>(
        ego, cav, nw1, nb1, nw2, nb2,
        sw0, sb0, cw0, cb0, kw0, kb0,
        sw1, sb1, cw1, cb1, kw1, kb1,
        fcw, fcb, (float*)d_out);
}